// Round 1
// baseline (1118.213 us; speedup 1.0000x reference)
//
#include <hip/hip_runtime.h>
#include <hip/hip_bf16.h>

#define B_  8
#define L_  4096
#define D_  2048
#define H_  16
#define HD_ 128
#define MK_ 1024

typedef __attribute__((ext_vector_type(8))) short short8;
typedef __attribute__((ext_vector_type(4))) float f32x4;

__device__ inline unsigned short f2bf(float f) {
  unsigned int u = __float_as_uint(f);
  unsigned int r = (u + 0x7fffu + ((u >> 16) & 1u)) >> 16;   // RNE
  return (unsigned short)r;
}

// ---------------------------------------------------------------- mask dtype
__global__ void detect_mask_kernel(const unsigned char* __restrict__ mask, int* flag) {
  __shared__ int cnt;
  if (threadIdx.x == 0) cnt = 0;
  __syncthreads();
  int local = 0;
  for (int i = threadIdx.x; i < B_ * L_; i += 256) local += (mask[i] != 0);
  atomicAdd(&cnt, local);
  __syncthreads();
  if (threadIdx.x == 0) {
    int t = 0;                       // default: 1-byte bool
    if (cnt == B_ * MK_)      t = 0; // u8: 8192 nonzero bytes
    else if (cnt == 2 * MK_)  t = 1; // i32: first 8192 ints = batches 0,1 -> 2048
    else if (cnt == 4 * MK_)  t = 2; // f32: 2 nonzero bytes per true -> 4096
    *flag = t;
  }
}

// ------------------------------------------------------- compaction / rowmap
__global__ void build_rowmap_kernel(const void* __restrict__ maskv,
                                    const int* __restrict__ flag,
                                    int* __restrict__ rowmap) {
  int b = blockIdx.x;
  int tid = threadIdx.x;
  int t = *flag;
  __shared__ int cnts[256];
  unsigned char loc[16];
  int c = 0;
  for (int j = 0; j < 16; ++j) {
    int pos = tid * 16 + j;
    int mv;
    if (t == 1)      mv = ((const int*)maskv)[b * L_ + pos] != 0;
    else if (t == 2) mv = ((const float*)maskv)[b * L_ + pos] != 0.0f;
    else             mv = ((const unsigned char*)maskv)[b * L_ + pos] != 0;
    loc[j] = (unsigned char)mv; c += mv;
  }
  cnts[tid] = c;
  __syncthreads();
  for (int off = 1; off < 256; off <<= 1) {
    int v = (tid >= off) ? cnts[tid - off] : 0;
    __syncthreads();
    cnts[tid] += v;
    __syncthreads();
  }
  int rank = cnts[tid] - c;
  for (int j = 0; j < 16; ++j) {
    if (loc[j]) {
      if (rank < MK_) rowmap[b * MK_ + rank] = b * L_ + tid * 16 + j;
      ++rank;
    }
  }
}

// -------------------------------------------------------------- copy x->out
__global__ __launch_bounds__(256) void copy_x_kernel(const float4* __restrict__ src,
                                                     float4* __restrict__ dst, int n4) {
  int i = blockIdx.x * 256 + threadIdx.x;
  int stride = gridDim.x * 256;
  for (; i < n4; i += stride) dst[i] = src[i];
}

// ------------------------------------------------------------- gather + bf16
__global__ __launch_bounds__(256) void gather_sig_kernel(const float* __restrict__ x,
                                                         const int* __restrict__ rowmap,
                                                         unsigned short* __restrict__ sig) {
  int row = blockIdx.x;
  const float* src = x + (size_t)rowmap[row] * D_;
  unsigned short* dst = sig + (size_t)row * D_;
  int tid = threadIdx.x;
  float4 a = ((const float4*)src)[tid * 2];
  float4 b4 = ((const float4*)src)[tid * 2 + 1];
  uint4 o;
  o.x = f2bf(a.x)  | ((unsigned)f2bf(a.y)  << 16);
  o.y = f2bf(a.z)  | ((unsigned)f2bf(a.w)  << 16);
  o.z = f2bf(b4.x) | ((unsigned)f2bf(b4.y) << 16);
  o.w = f2bf(b4.z) | ((unsigned)f2bf(b4.w) << 16);
  *(uint4*)(dst + tid * 8) = o;
}

// -------------------------------------------- register K/V rows (wave/output)
__global__ __launch_bounds__(256) void reg_kv_kernel(
    const float* __restrict__ reg, const float* __restrict__ Wrk, const float* __restrict__ brk,
    const float* __restrict__ Wrv, const float* __restrict__ brv,
    unsigned short* __restrict__ Kb, unsigned short* __restrict__ Vb) {
  int gw = (blockIdx.x * 256 + threadIdx.x) >> 6;  // 32768 waves
  int lane = threadIdx.x & 63;
  int mat = gw >> 14;
  int b = (gw >> 11) & 7;
  int n = gw & 2047;
  const float* W = mat ? Wrv : Wrk;
  const float* bias = mat ? brv : brk;
  const float* wrow = W + (size_t)n * D_;
  const float* rrow = reg + (size_t)b * D_;
  float s = 0.f;
  for (int j = 0; j < 8; ++j) {
    int e = j * 256 + lane * 4;
    float4 wv = *(const float4*)(wrow + e);
    float4 rv = *(const float4*)(rrow + e);
    s += wv.x * rv.x + wv.y * rv.y + wv.z * rv.z + wv.w * rv.w;
  }
  for (int off = 32; off; off >>= 1) s += __shfl_down(s, off);
  if (lane == 0) {
    unsigned short* dst = mat ? Vb : Kb;
    dst[((size_t)b * 1025 + 1024) * D_ + n] = f2bf(s + bias[n]);
  }
}

// ----------------------------------------------------------------- NT GEMM
// C[m,n] = (sum_k A[m,k]*Bw[n,k] + bias[n]) * alpha
// OUT_MODE 0: bf16, row=m   1: bf16, row=m+m/1024   2: f32, row=rowmap[m]
template<int OUT_MODE>
__global__ __launch_bounds__(256) void gemm_nt_kernel(
    const unsigned short* __restrict__ A, const float* __restrict__ Bw,
    const float* __restrict__ bias, void* __restrict__ Cout,
    const int* __restrict__ rowmap, float alpha) {
  const int K = D_;
  __shared__ __align__(16) unsigned short As[128][72];
  __shared__ __align__(16) unsigned short Bs[128][72];
  int tid = threadIdx.x;
  int lane = tid & 63, wid = tid >> 6;
  int g = lane >> 4, l15 = lane & 15;
  int wr = wid >> 1, wc = wid & 1;
  int m0 = blockIdx.x * 128, n0 = blockIdx.y * 128;

  f32x4 acc[4][4] = {};

  for (int k0 = 0; k0 < K; k0 += 64) {
    __syncthreads();
#pragma unroll
    for (int i = 0; i < 4; ++i) {
      int chunk = tid + i * 256;
      int r = chunk >> 3, c8 = (chunk & 7) * 8;
      uint4 v = *(const uint4*)(A + (size_t)(m0 + r) * K + k0 + c8);
      *(uint4*)(&As[r][c8]) = v;
    }
#pragma unroll
    for (int i = 0; i < 8; ++i) {
      int chunk = tid + i * 256;
      int r = chunk >> 4, c4 = (chunk & 15) * 4;
      float4 v = *(const float4*)(Bw + (size_t)(n0 + r) * K + k0 + c4);
      uint2 u;
      u.x = f2bf(v.x) | ((unsigned)f2bf(v.y) << 16);
      u.y = f2bf(v.z) | ((unsigned)f2bf(v.w) << 16);
      *(uint2*)(&Bs[r][c4]) = u;
    }
    __syncthreads();
#pragma unroll
    for (int kk = 0; kk < 64; kk += 32) {
      short8 af[4], bf[4];
#pragma unroll
      for (int mf = 0; mf < 4; ++mf)
        af[mf] = *(const short8*)(&As[wr * 64 + mf * 16 + l15][kk + g * 8]);
#pragma unroll
      for (int nf = 0; nf < 4; ++nf)
        bf[nf] = *(const short8*)(&Bs[wc * 64 + nf * 16 + l15][kk + g * 8]);
#pragma unroll
      for (int mf = 0; mf < 4; ++mf)
#pragma unroll
        for (int nf = 0; nf < 4; ++nf)
          acc[mf][nf] = __builtin_amdgcn_mfma_f32_16x16x32_bf16(af[mf], bf[nf], acc[mf][nf], 0, 0, 0);
    }
  }

#pragma unroll
  for (int mf = 0; mf < 4; ++mf) {
#pragma unroll
    for (int nf = 0; nf < 4; ++nf) {
      int nn = n0 + wc * 64 + nf * 16 + l15;
      float bvv = bias[nn];
#pragma unroll
      for (int r = 0; r < 4; ++r) {
        int m = m0 + wr * 64 + mf * 16 + g * 4 + r;
        float v = (acc[mf][nf][r] + bvv) * alpha;
        if (OUT_MODE == 0) {
          ((unsigned short*)Cout)[(size_t)m * D_ + nn] = f2bf(v);
        } else if (OUT_MODE == 1) {
          int row = m + (m >> 10);
          ((unsigned short*)Cout)[(size_t)row * D_ + nn] = f2bf(v);
        } else {
          int row = rowmap[m];
          ((float*)Cout)[(size_t)row * D_ + nn] = v;
        }
      }
    }
  }
}

// ----------------------------------------------------------- flash attention
__global__ __launch_bounds__(256) void attn_kernel(
    const unsigned short* __restrict__ Qb, const unsigned short* __restrict__ Kb,
    const unsigned short* __restrict__ Vb, unsigned short* __restrict__ Ob) {
  int bx = blockIdx.x;
  int qt = bx & 15;
  int h = (bx >> 4) & 15;
  int b = bx >> 8;
  int tid = threadIdx.x, lane = tid & 63, w = tid >> 6;
  int g = lane >> 4, l15 = lane & 15;
  int q0 = qt * 64;

  __shared__ __align__(16) unsigned short Ks[64][136];
  __shared__ __align__(16) unsigned short Vts[128][72];
  __shared__ __align__(16) unsigned short Ps[4][16][72];

  short8 qf[4];
  {
    const unsigned short* qrow = Qb + (size_t)(b * MK_ + q0 + w * 16 + l15) * D_ + h * HD_;
#pragma unroll
    for (int kk = 0; kk < 4; ++kk) qf[kk] = *(const short8*)(qrow + kk * 32 + g * 8);
  }

  f32x4 oacc[8] = {};
  float mrow[4], lrow[4];
#pragma unroll
  for (int r = 0; r < 4; ++r) { mrow[r] = -__builtin_inff(); lrow[r] = 0.f; }

  const size_t kvbase = ((size_t)b * 1025) * D_ + h * HD_;
  const float LOG2E = 1.4426950408889634f;

  for (int t = 0; t <= qt + 1; ++t) {
    int kv0 = (t <= qt) ? t * 64 : MK_;
    __syncthreads();
#pragma unroll
    for (int i = 0; i < 4; ++i) {
      int chunk = tid + i * 256;
      int r = chunk >> 4, c8 = (chunk & 15) * 8;
      uint4 v;
      if (kv0 + r <= MK_) v = *(const uint4*)(Kb + kvbase + (size_t)(kv0 + r) * D_ + c8);
      else { v.x = v.y = v.z = v.w = 0u; }
      *(uint4*)(&Ks[r][c8]) = v;
    }
#pragma unroll
    for (int i = 0; i < 8; ++i) {
      int chunk = tid + i * 256;
      int r = chunk >> 5, c4 = (chunk & 31) * 4;
      uint2 v;
      if (kv0 + r <= MK_) v = *(const uint2*)(Vb + kvbase + (size_t)(kv0 + r) * D_ + c4);
      else { v.x = v.y = 0u; }
      Vts[c4 + 0][r] = (unsigned short)(v.x & 0xffffu);
      Vts[c4 + 1][r] = (unsigned short)(v.x >> 16);
      Vts[c4 + 2][r] = (unsigned short)(v.y & 0xffffu);
      Vts[c4 + 3][r] = (unsigned short)(v.y >> 16);
    }
    __syncthreads();

    f32x4 sacc[4] = {};
#pragma unroll
    for (int kk = 0; kk < 4; ++kk) {
#pragma unroll
      for (int nf = 0; nf < 4; ++nf) {
        short8 kf = *(const short8*)(&Ks[nf * 16 + l15][kk * 32 + g * 8]);
        sacc[nf] = __builtin_amdgcn_mfma_f32_16x16x32_bf16(qf[kk], kf, sacc[nf], 0, 0, 0);
      }
    }

    if (t == qt) {
#pragma unroll
      for (int nf = 0; nf < 4; ++nf) {
        int col = nf * 16 + l15;
#pragma unroll
        for (int r = 0; r < 4; ++r) {
          int qlocal = w * 16 + g * 4 + r;
          if (col > qlocal) sacc[nf][r] = -1e9f;
        }
      }
    } else if (t == qt + 1) {
#pragma unroll
      for (int nf = 0; nf < 4; ++nf) {
        int col = nf * 16 + l15;
        if (col != 0) {
#pragma unroll
          for (int r = 0; r < 4; ++r) sacc[nf][r] = -1e9f;
        }
      }
    }

    float sf[4];
#pragma unroll
    for (int r = 0; r < 4; ++r) {
      float mx = fmaxf(fmaxf(sacc[0][r], sacc[1][r]), fmaxf(sacc[2][r], sacc[3][r]));
      mx = fmaxf(mx, __shfl_xor(mx, 1));
      mx = fmaxf(mx, __shfl_xor(mx, 2));
      mx = fmaxf(mx, __shfl_xor(mx, 4));
      mx = fmaxf(mx, __shfl_xor(mx, 8));
      float mnew = fmaxf(mrow[r], mx);
      sf[r] = exp2f((mrow[r] - mnew) * LOG2E);
      mrow[r] = mnew;
    }
    float rs[4] = {0.f, 0.f, 0.f, 0.f};
#pragma unroll
    for (int nf = 0; nf < 4; ++nf) {
#pragma unroll
      for (int r = 0; r < 4; ++r) {
        float p = exp2f((sacc[nf][r] - mrow[r]) * LOG2E);
        sacc[nf][r] = p;
        rs[r] += p;
      }
    }
#pragma unroll
    for (int r = 0; r < 4; ++r) {
      float s = rs[r];
      s += __shfl_xor(s, 1);
      s += __shfl_xor(s, 2);
      s += __shfl_xor(s, 4);
      s += __shfl_xor(s, 8);
      lrow[r] = lrow[r] * sf[r] + s;
    }
#pragma unroll
    for (int i = 0; i < 8; ++i)
#pragma unroll
      for (int r = 0; r < 4; ++r) oacc[i][r] *= sf[r];

#pragma unroll
    for (int nf = 0; nf < 4; ++nf)
#pragma unroll
      for (int r = 0; r < 4; ++r)
        Ps[w][g * 4 + r][nf * 16 + l15] = f2bf(sacc[nf][r]);

#pragma unroll
    for (int kk = 0; kk < 2; ++kk) {
      short8 pf = *(const short8*)(&Ps[w][l15][kk * 32 + g * 8]);
#pragma unroll
      for (int nf = 0; nf < 8; ++nf) {
        short8 vf = *(const short8*)(&Vts[nf * 16 + l15][kk * 32 + g * 8]);
        oacc[nf] = __builtin_amdgcn_mfma_f32_16x16x32_bf16(pf, vf, oacc[nf], 0, 0, 0);
      }
    }
  }

#pragma unroll
  for (int nf = 0; nf < 8; ++nf) {
#pragma unroll
    for (int r = 0; r < 4; ++r) {
      size_t row = (size_t)b * MK_ + q0 + w * 16 + g * 4 + r;
      Ob[row * D_ + h * HD_ + nf * 16 + l15] = f2bf(oacc[nf][r] / lrow[r]);
    }
  }
}

// ------------------------------------------------------------------- launch
extern "C" void kernel_launch(void* const* d_in, const int* in_sizes, int n_in,
                              void* d_out, int out_size, void* d_ws, size_t ws_size,
                              hipStream_t stream) {
  const float* x    = (const float*)d_in[0];
  const void*  mask = d_in[1];
  const float* reg  = (const float*)d_in[2];
  const float* Wq   = (const float*)d_in[3];
  const float* bq   = (const float*)d_in[4];
  const float* Wk   = (const float*)d_in[5];
  const float* bk   = (const float*)d_in[6];
  const float* Wv   = (const float*)d_in[7];
  const float* bv   = (const float*)d_in[8];
  const float* Wrk  = (const float*)d_in[9];
  const float* brk  = (const float*)d_in[10];
  const float* Wrv  = (const float*)d_in[11];
  const float* brv  = (const float*)d_in[12];
  const float* Wo   = (const float*)d_in[13];
  const float* bo   = (const float*)d_in[14];

  char* ws = (char*)d_ws;
  int* flag   = (int*)ws;
  int* rowmap = (int*)(ws + 256);
  unsigned short* sig = (unsigned short*)(ws + 33280);
  unsigned short* Qb = sig + (size_t)8192 * 2048;
  unsigned short* Kb = Qb + (size_t)8192 * 2048;
  unsigned short* Vb = Kb + (size_t)8200 * 2048;
  unsigned short* Ob = Vb + (size_t)8200 * 2048;

  detect_mask_kernel<<<1, 256, 0, stream>>>((const unsigned char*)mask, flag);
  build_rowmap_kernel<<<8, 256, 0, stream>>>(mask, flag, rowmap);
  copy_x_kernel<<<4096, 256, 0, stream>>>((const float4*)x, (float4*)d_out, (B_ * L_ * D_) / 4);
  gather_sig_kernel<<<8192, 256, 0, stream>>>(x, rowmap, sig);
  reg_kv_kernel<<<8192, 256, 0, stream>>>(reg, Wrk, brk, Wrv, brv, Kb, Vb);

  const float inv_scale = 0.08838834764831845f;  // 1/sqrt(HD)
  dim3 gg(64, 16);
  gemm_nt_kernel<0><<<gg, 256, 0, stream>>>(sig, Wq, bq, Qb, nullptr, inv_scale);
  gemm_nt_kernel<1><<<gg, 256, 0, stream>>>(sig, Wk, bk, Kb, nullptr, 1.0f);
  gemm_nt_kernel<1><<<gg, 256, 0, stream>>>(sig, Wv, bv, Vb, nullptr, 1.0f);
  attn_kernel<<<2048, 256, 0, stream>>>(Qb, Kb, Vb, Ob);
  gemm_nt_kernel<2><<<gg, 256, 0, stream>>>(Ob, Wo, bo, d_out, rowmap, 1.0f);
}

// Round 2
// 744.089 us; speedup vs baseline: 1.5028x; 1.5028x over previous
//
#include <hip/hip_runtime.h>
#include <hip/hip_bf16.h>

#define B_  8
#define L_  4096
#define D_  2048
#define H_  16
#define HD_ 128
#define MK_ 1024
#define VTP 1040   // Vt row pitch (k dim, 1025 used + pad)

typedef __attribute__((ext_vector_type(8))) short short8;
typedef __attribute__((ext_vector_type(4))) float f32x4;

__device__ inline unsigned short f2bf(float f) {
  unsigned int u = __float_as_uint(f);
  unsigned int r = (u + 0x7fffu + ((u >> 16) & 1u)) >> 16;   // RNE
  return (unsigned short)r;
}

__device__ __forceinline__ void gload_lds16(const void* g, void* l) {
  __builtin_amdgcn_global_load_lds(
      (const __attribute__((address_space(1))) void*)g,
      (__attribute__((address_space(3))) void*)l, 16, 0, 0);
}

// ---------------------------------------------------------------- mask dtype
__global__ void detect_mask_kernel(const unsigned char* __restrict__ mask, int* flag,
                                   unsigned char* __restrict__ sel) {
  __shared__ int cnt;
  if (threadIdx.x == 0) cnt = 0;
  __syncthreads();
  // clear sel bitmap (32768 bytes)
  for (int i = threadIdx.x; i < (B_ * L_) / 16; i += 256) ((int4*)sel)[i] = make_int4(0, 0, 0, 0);
  int local = 0;
  for (int i = threadIdx.x; i < B_ * L_; i += 256) local += (mask[i] != 0);
  atomicAdd(&cnt, local);
  __syncthreads();
  if (threadIdx.x == 0) {
    int t = 0;
    if (cnt == B_ * MK_)      t = 0; // u8 bool
    else if (cnt == 2 * MK_)  t = 1; // i32
    else if (cnt == 4 * MK_)  t = 2; // f32
    *flag = t;
  }
}

// ------------------------------------------------------- compaction / rowmap
__global__ void build_rowmap_kernel(const void* __restrict__ maskv,
                                    const int* __restrict__ flag,
                                    int* __restrict__ rowmap,
                                    unsigned char* __restrict__ sel) {
  int b = blockIdx.x;
  int tid = threadIdx.x;
  int t = *flag;
  __shared__ int cnts[256];
  unsigned char loc[16];
  int c = 0;
  for (int j = 0; j < 16; ++j) {
    int pos = tid * 16 + j;
    int mv;
    if (t == 1)      mv = ((const int*)maskv)[b * L_ + pos] != 0;
    else if (t == 2) mv = ((const float*)maskv)[b * L_ + pos] != 0.0f;
    else             mv = ((const unsigned char*)maskv)[b * L_ + pos] != 0;
    loc[j] = (unsigned char)mv; c += mv;
  }
  cnts[tid] = c;
  __syncthreads();
  for (int off = 1; off < 256; off <<= 1) {
    int v = (tid >= off) ? cnts[tid - off] : 0;
    __syncthreads();
    cnts[tid] += v;
    __syncthreads();
  }
  int rank = cnts[tid] - c;
  for (int j = 0; j < 16; ++j) {
    if (loc[j]) {
      if (rank < MK_) {
        int grow = b * L_ + tid * 16 + j;
        rowmap[b * MK_ + rank] = grow;
        sel[grow] = 1;
      }
      ++rank;
    }
  }
}

// -------------------------------------------------- copy x->out (skip selected)
__global__ __launch_bounds__(256) void copy_x_kernel(const float4* __restrict__ src,
                                                     float4* __restrict__ dst,
                                                     const unsigned char* __restrict__ sel) {
  int row = blockIdx.x;
  if (sel[row]) return;
  size_t base = (size_t)row * 512 + threadIdx.x;
  dst[base] = src[base];
  dst[base + 256] = src[base + 256];
}

// ------------------------------------------------------------- gather + bf16
__global__ __launch_bounds__(256) void gather_sig_kernel(const float* __restrict__ x,
                                                         const int* __restrict__ rowmap,
                                                         unsigned short* __restrict__ sig) {
  int row = blockIdx.x;
  const float* src = x + (size_t)rowmap[row] * D_;
  unsigned short* dst = sig + (size_t)row * D_;
  int tid = threadIdx.x;
  float4 a = ((const float4*)src)[tid * 2];
  float4 b4 = ((const float4*)src)[tid * 2 + 1];
  uint4 o;
  o.x = f2bf(a.x)  | ((unsigned)f2bf(a.y)  << 16);
  o.y = f2bf(a.z)  | ((unsigned)f2bf(a.w)  << 16);
  o.z = f2bf(b4.x) | ((unsigned)f2bf(b4.y) << 16);
  o.w = f2bf(b4.z) | ((unsigned)f2bf(b4.w) << 16);
  *(uint4*)(dst + tid * 8) = o;
}

// ---------------------------------------------------------- f32 -> bf16 weights
__global__ __launch_bounds__(256) void conv_bf16_kernel(const float* __restrict__ W,
                                                        unsigned short* __restrict__ Wb) {
  size_t i = ((size_t)blockIdx.x * 256 + threadIdx.x) * 8;
  float4 a = *(const float4*)(W + i);
  float4 b4 = *(const float4*)(W + i + 4);
  uint4 o;
  o.x = f2bf(a.x)  | ((unsigned)f2bf(a.y)  << 16);
  o.y = f2bf(a.z)  | ((unsigned)f2bf(a.w)  << 16);
  o.z = f2bf(b4.x) | ((unsigned)f2bf(b4.y) << 16);
  o.w = f2bf(b4.z) | ((unsigned)f2bf(b4.w) << 16);
  *(uint4*)(Wb + i) = o;
}

// -------------------------------------------- register K/V rows
__global__ __launch_bounds__(256) void reg_kv_kernel(
    const float* __restrict__ reg, const float* __restrict__ Wrk, const float* __restrict__ brk,
    const float* __restrict__ Wrv, const float* __restrict__ brv,
    unsigned short* __restrict__ Kb, unsigned short* __restrict__ Vt) {
  int gw = (blockIdx.x * 256 + threadIdx.x) >> 6;
  int lane = threadIdx.x & 63;
  int mat = gw >> 14;
  int b = (gw >> 11) & 7;
  int n = gw & 2047;
  const float* W = mat ? Wrv : Wrk;
  const float* bias = mat ? brv : brk;
  const float* wrow = W + (size_t)n * D_;
  const float* rrow = reg + (size_t)b * D_;
  float s = 0.f;
  for (int j = 0; j < 8; ++j) {
    int e = j * 256 + lane * 4;
    float4 wv = *(const float4*)(wrow + e);
    float4 rv = *(const float4*)(rrow + e);
    s += wv.x * rv.x + wv.y * rv.y + wv.z * rv.z + wv.w * rv.w;
  }
  for (int off = 32; off; off >>= 1) s += __shfl_down(s, off);
  if (lane == 0) {
    unsigned short v = f2bf(s + bias[n]);
    if (mat) {
      int hq = n >> 7, hd = n & 127;
      Vt[(((size_t)b * 16 + hq) * 128 + hd) * VTP + 1024] = v;
    } else {
      Kb[((size_t)b * 1025 + 1024) * D_ + n] = v;
    }
  }
}

// ----------------------------------------------------------------- NT GEMM
// C[m,n] = (sum_k A[m,k]*Bw[n,k] + bias[n]) * alpha ; A,Bw bf16 row-major (k-contig)
// OUT_MODE 0: bf16 row=m | 1: bf16 row=m+(m>>10) | 2: f32 row=rowmap[m] | 3: Vt transposed
template<int OUT_MODE>
__global__ __launch_bounds__(256) void gemm_bf_kernel(
    const unsigned short* __restrict__ A, const unsigned short* __restrict__ Bw,
    const float* __restrict__ bias, void* __restrict__ Cout,
    const int* __restrict__ rowmap, float alpha) {
  __shared__ __align__(16) unsigned short As[128 * 64];
  __shared__ __align__(16) unsigned short Bs[128 * 64];
  int tid = threadIdx.x;
  int lane = tid & 63, w = tid >> 6;
  int g = lane >> 4, l15 = lane & 15;
  int wr = w >> 1, wc = w & 1;

  // XCD-aware bijective swizzle: grid 1024 (%8==0)
  int bid = blockIdx.x;
  int wg = (bid & 7) * 128 + (bid >> 3);
  int m0 = (wg & 63) * 128, n0 = (wg >> 6) * 128;

  f32x4 acc[4][4] = {};

  for (int k0 = 0; k0 < D_; k0 += 64) {
    __syncthreads();
#pragma unroll
    for (int i = 0; i < 4; ++i) {
      int ib = w * 4 + i;
      int row = ib * 8 + (lane >> 3);
      int sl = (lane & 7) ^ (row & 7);          // inverse-swizzled source slot
      gload_lds16(A  + (size_t)(m0 + row) * D_ + k0 + sl * 8, As + ib * 512);
      gload_lds16(Bw + (size_t)(n0 + row) * D_ + k0 + sl * 8, Bs + ib * 512);
    }
    __syncthreads();
#pragma unroll
    for (int kk = 0; kk < 2; ++kk) {
      short8 af[4], bf[4];
#pragma unroll
      for (int mf = 0; mf < 4; ++mf) {
        int r = wr * 64 + mf * 16 + l15;
        int sw = (kk * 4 + g) ^ (r & 7);
        af[mf] = *(const short8*)(As + r * 64 + sw * 8);
      }
#pragma unroll
      for (int nf = 0; nf < 4; ++nf) {
        int r = wc * 64 + nf * 16 + l15;
        int sw = (kk * 4 + g) ^ (r & 7);
        bf[nf] = *(const short8*)(Bs + r * 64 + sw * 8);
      }
#pragma unroll
      for (int mf = 0; mf < 4; ++mf)
#pragma unroll
        for (int nf = 0; nf < 4; ++nf)
          acc[mf][nf] = __builtin_amdgcn_mfma_f32_16x16x32_bf16(af[mf], bf[nf], acc[mf][nf], 0, 0, 0);
    }
  }

#pragma unroll
  for (int mf = 0; mf < 4; ++mf) {
#pragma unroll
    for (int nf = 0; nf < 4; ++nf) {
      int nn = n0 + wc * 64 + nf * 16 + l15;
      float bvv = bias[nn];
      if (OUT_MODE == 3) {
        int m = m0 + wr * 64 + mf * 16 + g * 4;
        int bb = m >> 10, tok = m & 1023;
        int hq = nn >> 7, hd = nn & 127;
        size_t base = (((size_t)bb * 16 + hq) * 128 + hd) * VTP + tok;
        uint2 u;
        u.x = f2bf(acc[mf][nf][0] + bvv) | ((unsigned)f2bf(acc[mf][nf][1] + bvv) << 16);
        u.y = f2bf(acc[mf][nf][2] + bvv) | ((unsigned)f2bf(acc[mf][nf][3] + bvv) << 16);
        *(uint2*)((unsigned short*)Cout + base) = u;
      } else {
#pragma unroll
        for (int r = 0; r < 4; ++r) {
          int m = m0 + wr * 64 + mf * 16 + g * 4 + r;
          float v = (acc[mf][nf][r] + bvv) * alpha;
          if (OUT_MODE == 0) {
            ((unsigned short*)Cout)[(size_t)m * D_ + nn] = f2bf(v);
          } else if (OUT_MODE == 1) {
            int row = m + (m >> 10);
            ((unsigned short*)Cout)[(size_t)row * D_ + nn] = f2bf(v);
          } else {
            int row = rowmap[m];
            ((float*)Cout)[(size_t)row * D_ + nn] = v;
          }
        }
      }
    }
  }
}

// ----------------------------------------------------------- flash attention
// Kb: [b][1025][2048] bf16 ; Vt: [(b*16+h)*128+d][VTP] bf16 (k-contig, transposed)
__global__ __launch_bounds__(256) void attn_kernel(
    const unsigned short* __restrict__ Qb, const unsigned short* __restrict__ Kb,
    const unsigned short* __restrict__ Vt, unsigned short* __restrict__ Ob) {
  int bx = blockIdx.x;
  int qt = bx & 15;
  int h = (bx >> 4) & 15;
  int b = bx >> 8;
  int bh = b * 16 + h;
  int tid = threadIdx.x, lane = tid & 63, w = tid >> 6;
  int g = lane >> 4, l15 = lane & 15;
  int q0 = qt * 64;

  __shared__ __align__(16) unsigned short Ks[64 * 128];   // [kv 64][hd 128] swizzled
  __shared__ __align__(16) unsigned short Vts[128 * 64];  // [d 128][kv 64] swizzled
  __shared__ __align__(16) unsigned short Ps[4][16][72];

  short8 qf[4];
  {
    const unsigned short* qrow = Qb + (size_t)(b * MK_ + q0 + w * 16 + l15) * D_ + h * HD_;
#pragma unroll
    for (int kk = 0; kk < 4; ++kk) qf[kk] = *(const short8*)(qrow + kk * 32 + g * 8);
  }

  f32x4 oacc[8] = {};
  float mrow[4], lrow[4];
#pragma unroll
  for (int r = 0; r < 4; ++r) { mrow[r] = -__builtin_inff(); lrow[r] = 0.f; }

  const unsigned short* Kbase = Kb + (size_t)b * 1025 * D_ + h * HD_;
  const unsigned short* Vbase = Vt + (size_t)bh * 128 * VTP;
  const float LOG2E = 1.4426950408889634f;

  for (int t = 0; t <= qt + 1; ++t) {
    int kv0 = (t <= qt) ? t * 64 : MK_;
    __syncthreads();
    // stage K: 16 x 1KB issues (4/wave); rows 4 per issue, 16 slots/row
#pragma unroll
    for (int i = 0; i < 4; ++i) {
      int ib = w * 4 + i;
      int row = ib * 4 + (lane >> 4);
      int sl = (lane & 15) ^ (row & 7);
      int krow = kv0 + row; if (krow > MK_) krow = MK_;
      gload_lds16(Kbase + (size_t)krow * D_ + sl * 8, Ks + ib * 512);
    }
    // stage V^T: 16 x 1KB issues; rows(d) 8 per issue, 8 slots/row
#pragma unroll
    for (int i = 0; i < 4; ++i) {
      int ib = w * 4 + i;
      int row = ib * 8 + (lane >> 3);
      int sl = (lane & 7) ^ (row & 7);
      gload_lds16(Vbase + (size_t)row * VTP + kv0 + sl * 8, Vts + ib * 512);
    }
    __syncthreads();

    f32x4 sacc[4] = {};
#pragma unroll
    for (int kk = 0; kk < 4; ++kk) {
#pragma unroll
      for (int nf = 0; nf < 4; ++nf) {
        int krow = nf * 16 + l15;
        int sw = (kk * 4 + g) ^ (krow & 7);
        short8 kf = *(const short8*)(Ks + krow * 128 + sw * 8);
        sacc[nf] = __builtin_amdgcn_mfma_f32_16x16x32_bf16(qf[kk], kf, sacc[nf], 0, 0, 0);
      }
    }

    if (t == qt) {
#pragma unroll
      for (int nf = 0; nf < 4; ++nf) {
        int col = nf * 16 + l15;
#pragma unroll
        for (int r = 0; r < 4; ++r) {
          int qlocal = w * 16 + g * 4 + r;
          if (col > qlocal) sacc[nf][r] = -1e9f;
        }
      }
    } else if (t == qt + 1) {
#pragma unroll
      for (int nf = 0; nf < 4; ++nf) {
        int col = nf * 16 + l15;
        if (col != 0) {
#pragma unroll
          for (int r = 0; r < 4; ++r) sacc[nf][r] = -1e9f;
        }
      }
    }

    float sf[4];
#pragma unroll
    for (int r = 0; r < 4; ++r) {
      float mx = fmaxf(fmaxf(sacc[0][r], sacc[1][r]), fmaxf(sacc[2][r], sacc[3][r]));
      mx = fmaxf(mx, __shfl_xor(mx, 1));
      mx = fmaxf(mx, __shfl_xor(mx, 2));
      mx = fmaxf(mx, __shfl_xor(mx, 4));
      mx = fmaxf(mx, __shfl_xor(mx, 8));
      float mnew = fmaxf(mrow[r], mx);
      sf[r] = exp2f((mrow[r] - mnew) * LOG2E);
      mrow[r] = mnew;
    }
    float rs[4] = {0.f, 0.f, 0.f, 0.f};
#pragma unroll
    for (int nf = 0; nf < 4; ++nf) {
#pragma unroll
      for (int r = 0; r < 4; ++r) {
        float p = exp2f((sacc[nf][r] - mrow[r]) * LOG2E);
        sacc[nf][r] = p;
        rs[r] += p;
      }
    }
#pragma unroll
    for (int r = 0; r < 4; ++r) {
      float s = rs[r];
      s += __shfl_xor(s, 1);
      s += __shfl_xor(s, 2);
      s += __shfl_xor(s, 4);
      s += __shfl_xor(s, 8);
      lrow[r] = lrow[r] * sf[r] + s;
    }
#pragma unroll
    for (int i = 0; i < 8; ++i)
#pragma unroll
      for (int r = 0; r < 4; ++r) oacc[i][r] *= sf[r];

#pragma unroll
    for (int nf = 0; nf < 4; ++nf)
#pragma unroll
      for (int r = 0; r < 4; ++r)
        Ps[w][g * 4 + r][nf * 16 + l15] = f2bf(sacc[nf][r]);

#pragma unroll
    for (int kk = 0; kk < 2; ++kk) {
      short8 pf = *(const short8*)(&Ps[w][l15][kk * 32 + g * 8]);
#pragma unroll
      for (int nf = 0; nf < 8; ++nf) {
        int vrow = nf * 16 + l15;
        int sw = (kk * 4 + g) ^ (vrow & 7);
        short8 vf = *(const short8*)(Vts + vrow * 64 + sw * 8);
        oacc[nf] = __builtin_amdgcn_mfma_f32_16x16x32_bf16(pf, vf, oacc[nf], 0, 0, 0);
      }
    }
  }

#pragma unroll
  for (int nf = 0; nf < 8; ++nf) {
#pragma unroll
    for (int r = 0; r < 4; ++r) {
      size_t row = (size_t)b * MK_ + q0 + w * 16 + g * 4 + r;
      Ob[row * D_ + h * HD_ + nf * 16 + l15] = f2bf(oacc[nf][r] / lrow[r]);
    }
  }
}

// ------------------------------------------------------------------- launch
extern "C" void kernel_launch(void* const* d_in, const int* in_sizes, int n_in,
                              void* d_out, int out_size, void* d_ws, size_t ws_size,
                              hipStream_t stream) {
  const float* x    = (const float*)d_in[0];
  const void*  mask = d_in[1];
  const float* reg  = (const float*)d_in[2];
  const float* Wq   = (const float*)d_in[3];
  const float* bq   = (const float*)d_in[4];
  const float* Wk   = (const float*)d_in[5];
  const float* bk   = (const float*)d_in[6];
  const float* Wv   = (const float*)d_in[7];
  const float* bv   = (const float*)d_in[8];
  const float* Wrk  = (const float*)d_in[9];
  const float* brk  = (const float*)d_in[10];
  const float* Wrv  = (const float*)d_in[11];
  const float* brv  = (const float*)d_in[12];
  const float* Wo   = (const float*)d_in[13];
  const float* bo   = (const float*)d_in[14];

  char* ws = (char*)d_ws;
  int* flag            = (int*)ws;                       // 256 B
  int* rowmap          = (int*)(ws + 256);               // 32768 B
  unsigned char* sel   = (unsigned char*)(ws + 33024);   // 32768 B
  char* p = ws + 66048;
  unsigned short* sig = (unsigned short*)p;              p += (size_t)8192 * 2048 * 2;
  unsigned short* Qb  = (unsigned short*)p;              p += (size_t)8192 * 2048 * 2;
  unsigned short* Kb  = (unsigned short*)p;              p += (size_t)8200 * 2048 * 2;
  unsigned short* Vtb = (unsigned short*)p;              p += ((size_t)16384 * VTP + 64) * 2;
  unsigned short* Wbf = (unsigned short*)p;              p += (size_t)2048 * 2048 * 2;
  unsigned short* Ob  = sig;  // sig dead after V-GEMM; attn writes Ob afterwards

  detect_mask_kernel<<<1, 256, 0, stream>>>((const unsigned char*)mask, flag, sel);
  build_rowmap_kernel<<<8, 256, 0, stream>>>(mask, flag, rowmap, sel);
  copy_x_kernel<<<B_ * L_, 256, 0, stream>>>((const float4*)x, (float4*)d_out, sel);
  gather_sig_kernel<<<8192, 256, 0, stream>>>(x, rowmap, sig);
  reg_kv_kernel<<<8192, 256, 0, stream>>>(reg, Wrk, brk, Wrv, brv, Kb, Vtb);

  const float inv_scale = 0.08838834764831845f;  // 1/sqrt(HD)
  conv_bf16_kernel<<<2048, 256, 0, stream>>>(Wq, Wbf);
  gemm_bf_kernel<0><<<1024, 256, 0, stream>>>(sig, Wbf, bq, Qb, nullptr, inv_scale);
  conv_bf16_kernel<<<2048, 256, 0, stream>>>(Wk, Wbf);
  gemm_bf_kernel<1><<<1024, 256, 0, stream>>>(sig, Wbf, bk, Kb, nullptr, 1.0f);
  conv_bf16_kernel<<<2048, 256, 0, stream>>>(Wv, Wbf);
  gemm_bf_kernel<3><<<1024, 256, 0, stream>>>(sig, Wbf, bv, Vtb, nullptr, 1.0f);
  attn_kernel<<<2048, 256, 0, stream>>>(Qb, Kb, Vtb, Ob);
  conv_bf16_kernel<<<2048, 256, 0, stream>>>(Wo, Wbf);
  gemm_bf_kernel<2><<<1024, 256, 0, stream>>>(Ob, Wbf, bo, d_out, rowmap, 1.0f);
}

// Round 3
// 657.708 us; speedup vs baseline: 1.7002x; 1.1313x over previous
//
#include <hip/hip_runtime.h>
#include <hip/hip_bf16.h>

#define B_  8
#define L_  4096
#define D_  2048
#define H_  16
#define HD_ 128
#define MK_ 1024
#define VTP 1040   // Vt row pitch (k dim, 1025 used + pad)

typedef __attribute__((ext_vector_type(8))) short short8;
typedef __attribute__((ext_vector_type(4))) float f32x4;

__device__ inline unsigned short f2bf(float f) {
  unsigned int u = __float_as_uint(f);
  unsigned int r = (u + 0x7fffu + ((u >> 16) & 1u)) >> 16;   // RNE
  return (unsigned short)r;
}

__device__ __forceinline__ void gload_lds16(const void* g, void* l) {
  __builtin_amdgcn_global_load_lds(
      (const __attribute__((address_space(1))) void*)g,
      (__attribute__((address_space(3))) void*)l, 16, 0, 0);
}

// ---------------------------------------------------------------- mask dtype
__global__ void detect_mask_kernel(const unsigned char* __restrict__ mask, int* flag,
                                   unsigned char* __restrict__ sel) {
  __shared__ int cnt;
  if (threadIdx.x == 0) cnt = 0;
  __syncthreads();
  for (int i = threadIdx.x; i < (B_ * L_) / 16; i += 256) ((int4*)sel)[i] = make_int4(0, 0, 0, 0);
  int local = 0;
  for (int i = threadIdx.x; i < B_ * L_; i += 256) local += (mask[i] != 0);
  atomicAdd(&cnt, local);
  __syncthreads();
  if (threadIdx.x == 0) {
    int t = 0;
    if (cnt == B_ * MK_)      t = 0; // u8 bool
    else if (cnt == 2 * MK_)  t = 1; // i32
    else if (cnt == 4 * MK_)  t = 2; // f32
    *flag = t;
  }
}

// ------------------------------------------------------- compaction / rowmap
__global__ void build_rowmap_kernel(const void* __restrict__ maskv,
                                    const int* __restrict__ flag,
                                    int* __restrict__ rowmap,
                                    unsigned char* __restrict__ sel) {
  int b = blockIdx.x;
  int tid = threadIdx.x;
  int t = *flag;
  __shared__ int cnts[256];
  unsigned char loc[16];
  int c = 0;
  for (int j = 0; j < 16; ++j) {
    int pos = tid * 16 + j;
    int mv;
    if (t == 1)      mv = ((const int*)maskv)[b * L_ + pos] != 0;
    else if (t == 2) mv = ((const float*)maskv)[b * L_ + pos] != 0.0f;
    else             mv = ((const unsigned char*)maskv)[b * L_ + pos] != 0;
    loc[j] = (unsigned char)mv; c += mv;
  }
  cnts[tid] = c;
  __syncthreads();
  for (int off = 1; off < 256; off <<= 1) {
    int v = (tid >= off) ? cnts[tid - off] : 0;
    __syncthreads();
    cnts[tid] += v;
    __syncthreads();
  }
  int rank = cnts[tid] - c;
  for (int j = 0; j < 16; ++j) {
    if (loc[j]) {
      if (rank < MK_) {
        int grow = b * L_ + tid * 16 + j;
        rowmap[b * MK_ + rank] = grow;
        sel[grow] = 1;
      }
      ++rank;
    }
  }
}

// -------------------------------------------------- copy x->out (skip selected)
__global__ __launch_bounds__(256) void copy_x_kernel(const float4* __restrict__ src,
                                                     float4* __restrict__ dst,
                                                     const unsigned char* __restrict__ sel) {
  int row = blockIdx.x;
  if (sel[row]) return;
  size_t base = (size_t)row * 512 + threadIdx.x;
  dst[base] = src[base];
  dst[base + 256] = src[base + 256];
}

// ------------------------------------------------------------- gather + bf16
__global__ __launch_bounds__(256) void gather_sig_kernel(const float* __restrict__ x,
                                                         const int* __restrict__ rowmap,
                                                         unsigned short* __restrict__ sig) {
  int row = blockIdx.x;
  const float* src = x + (size_t)rowmap[row] * D_;
  unsigned short* dst = sig + (size_t)row * D_;
  int tid = threadIdx.x;
  float4 a = ((const float4*)src)[tid * 2];
  float4 b4 = ((const float4*)src)[tid * 2 + 1];
  uint4 o;
  o.x = f2bf(a.x)  | ((unsigned)f2bf(a.y)  << 16);
  o.y = f2bf(a.z)  | ((unsigned)f2bf(a.w)  << 16);
  o.z = f2bf(b4.x) | ((unsigned)f2bf(b4.y) << 16);
  o.w = f2bf(b4.z) | ((unsigned)f2bf(b4.w) << 16);
  *(uint4*)(dst + tid * 8) = o;
}

// ---------------------------------------------------------- f32 -> bf16 weights
__global__ __launch_bounds__(256) void conv_bf16_kernel(const float* __restrict__ W,
                                                        unsigned short* __restrict__ Wb) {
  size_t i = ((size_t)blockIdx.x * 256 + threadIdx.x) * 8;
  float4 a = *(const float4*)(W + i);
  float4 b4 = *(const float4*)(W + i + 4);
  uint4 o;
  o.x = f2bf(a.x)  | ((unsigned)f2bf(a.y)  << 16);
  o.y = f2bf(a.z)  | ((unsigned)f2bf(a.w)  << 16);
  o.z = f2bf(b4.x) | ((unsigned)f2bf(b4.y) << 16);
  o.w = f2bf(b4.z) | ((unsigned)f2bf(b4.w) << 16);
  *(uint4*)(Wb + i) = o;
}

// -------------------------------------------- register K/V rows (batched over b)
__global__ __launch_bounds__(256) void reg_kv_kernel(
    const float* __restrict__ reg, const float* __restrict__ Wrk, const float* __restrict__ brk,
    const float* __restrict__ Wrv, const float* __restrict__ brv,
    unsigned short* __restrict__ Kb, unsigned short* __restrict__ Vt) {
  int gw = (blockIdx.x * 256 + threadIdx.x) >> 6;  // 4096 waves
  int lane = threadIdx.x & 63;
  int mat = gw >> 11;
  int n = gw & 2047;
  const float* W = mat ? Wrv : Wrk;
  const float* wrow = W + (size_t)n * D_;
  float s[8] = {};
  for (int j = 0; j < 8; ++j) {
    int e = j * 256 + lane * 4;
    float4 wv = *(const float4*)(wrow + e);
#pragma unroll
    for (int b = 0; b < 8; ++b) {
      float4 rv = *(const float4*)(reg + (size_t)b * D_ + e);
      s[b] += wv.x * rv.x + wv.y * rv.y + wv.z * rv.z + wv.w * rv.w;
    }
  }
#pragma unroll
  for (int off = 32; off; off >>= 1)
#pragma unroll
    for (int b = 0; b < 8; ++b) s[b] += __shfl_down(s[b], off);
  if (lane == 0) {
    float bias = (mat ? brv : brk)[n];
#pragma unroll
    for (int b = 0; b < 8; ++b) {
      unsigned short v = f2bf(s[b] + bias);
      if (mat) {
        Vt[(((size_t)b * 16 + (n >> 7)) * 128 + (n & 127)) * VTP + 1024] = v;
      } else {
        Kb[((size_t)b * 1025 + 1024) * D_ + n] = v;
      }
    }
  }
}

// ----------------------------------------------------------------- NT GEMM
// C[m,n] = (sum_k A[m,k]*Bw[n,k] + bias[n]) * alpha ; A,Bw bf16 row-major (k-contig)
// OUT_MODE 0: bf16 row=m | 1: bf16 row=m+(m>>10) | 2: f32 row=rowmap[m] | 3: Vt transposed
template<int OUT_MODE>
__global__ __launch_bounds__(256) void gemm_bf_kernel(
    const unsigned short* __restrict__ A, const unsigned short* __restrict__ Bw,
    const float* __restrict__ bias, void* __restrict__ Cout,
    const int* __restrict__ rowmap, float alpha) {
  __shared__ __align__(16) unsigned short As[128 * 64];
  __shared__ __align__(16) unsigned short Bs[128 * 64];
  int tid = threadIdx.x;
  int lane = tid & 63, w = tid >> 6;
  int g = lane >> 4, l15 = lane & 15;
  int wr = w >> 1, wc = w & 1;

  int bid = blockIdx.x;
  int wg = (bid & 7) * 128 + (bid >> 3);
  int m0 = (wg & 63) * 128, n0 = (wg >> 6) * 128;

  f32x4 acc[4][4] = {};

  for (int k0 = 0; k0 < D_; k0 += 64) {
    __syncthreads();
#pragma unroll
    for (int i = 0; i < 4; ++i) {
      int ib = w * 4 + i;
      int row = ib * 8 + (lane >> 3);
      int sl = (lane & 7) ^ (row & 7);
      gload_lds16(A  + (size_t)(m0 + row) * D_ + k0 + sl * 8, As + ib * 512);
      gload_lds16(Bw + (size_t)(n0 + row) * D_ + k0 + sl * 8, Bs + ib * 512);
    }
    __syncthreads();
#pragma unroll
    for (int kk = 0; kk < 2; ++kk) {
      short8 af[4], bf[4];
#pragma unroll
      for (int mf = 0; mf < 4; ++mf) {
        int r = wr * 64 + mf * 16 + l15;
        int sw = (kk * 4 + g) ^ (r & 7);
        af[mf] = *(const short8*)(As + r * 64 + sw * 8);
      }
#pragma unroll
      for (int nf = 0; nf < 4; ++nf) {
        int r = wc * 64 + nf * 16 + l15;
        int sw = (kk * 4 + g) ^ (r & 7);
        bf[nf] = *(const short8*)(Bs + r * 64 + sw * 8);
      }
#pragma unroll
      for (int mf = 0; mf < 4; ++mf)
#pragma unroll
        for (int nf = 0; nf < 4; ++nf)
          acc[mf][nf] = __builtin_amdgcn_mfma_f32_16x16x32_bf16(af[mf], bf[nf], acc[mf][nf], 0, 0, 0);
    }
  }

#pragma unroll
  for (int mf = 0; mf < 4; ++mf) {
#pragma unroll
    for (int nf = 0; nf < 4; ++nf) {
      int nn = n0 + wc * 64 + nf * 16 + l15;
      float bvv = bias[nn];
      if (OUT_MODE == 3) {
        int m = m0 + wr * 64 + mf * 16 + g * 4;
        int bb = m >> 10, tok = m & 1023;
        int hq = nn >> 7, hd = nn & 127;
        size_t base = (((size_t)bb * 16 + hq) * 128 + hd) * VTP + tok;
        uint2 u;
        u.x = f2bf(acc[mf][nf][0] + bvv) | ((unsigned)f2bf(acc[mf][nf][1] + bvv) << 16);
        u.y = f2bf(acc[mf][nf][2] + bvv) | ((unsigned)f2bf(acc[mf][nf][3] + bvv) << 16);
        *(uint2*)((unsigned short*)Cout + base) = u;
      } else {
#pragma unroll
        for (int r = 0; r < 4; ++r) {
          int m = m0 + wr * 64 + mf * 16 + g * 4 + r;
          float v = (acc[mf][nf][r] + bvv) * alpha;
          if (OUT_MODE == 0) {
            ((unsigned short*)Cout)[(size_t)m * D_ + nn] = f2bf(v);
          } else if (OUT_MODE == 1) {
            int row = m + (m >> 10);
            ((unsigned short*)Cout)[(size_t)row * D_ + nn] = f2bf(v);
          } else {
            int row = rowmap[m];
            ((float*)Cout)[(size_t)row * D_ + nn] = v;
          }
        }
      }
    }
  }
}

// ----------------------------------------------------------- flash attention
// Q pre-scaled by 1/sqrt(HD)*log2(e) -> scores already in log2 domain.
// Kb: [b][1025][2048] bf16 ; Vt: [(b*16+h)*128+d][VTP] bf16 (k-contig, transposed)
// 8 waves, QBLK=128, K double-buffered (prefetch), V single-buffered (latency
// hidden under QK+softmax), counted vmcnt + raw s_barrier (T3/T4 pattern).
__device__ __forceinline__ void stage_k(const unsigned short* Kbase, unsigned short* dst,
                                        int kv0, int w, int lane) {
#pragma unroll
  for (int i = 0; i < 2; ++i) {
    int ib = w * 2 + i;
    int row = ib * 4 + (lane >> 4);
    int sl = (lane & 15) ^ (row & 7);
    int krow = kv0 + row; if (krow > MK_) krow = MK_;
    gload_lds16(Kbase + (size_t)krow * D_ + sl * 8, dst + ib * 512);
  }
}
__device__ __forceinline__ void stage_v(const unsigned short* Vbase, unsigned short* dst,
                                        int kv0, int w, int lane) {
#pragma unroll
  for (int i = 0; i < 2; ++i) {
    int ib = w * 2 + i;
    int row = ib * 8 + (lane >> 3);
    int sl = (lane & 7) ^ (row & 7);
    gload_lds16(Vbase + (size_t)row * VTP + kv0 + sl * 8, dst + ib * 512);
  }
}

__global__ __launch_bounds__(512) void attn_kernel(
    const unsigned short* __restrict__ Qb, const unsigned short* __restrict__ Kb,
    const unsigned short* __restrict__ Vt, unsigned short* __restrict__ Ob) {
  int bx = blockIdx.x;
  int qi = 7 - (bx >> 7);          // heavy blocks first
  int bh = bx & 127;
  int b = bh >> 4, h = bh & 15;
  int tid = threadIdx.x, lane = tid & 63, w = tid >> 6;
  int g = lane >> 4, l15 = lane & 15;
  int q0 = qi * 128;
  int nt = 2 * qi + 3;             // causal tiles + register tile

  __shared__ __align__(16) unsigned short Ks[2][64 * 128];
  __shared__ __align__(16) unsigned short Vts[128 * 64];
  __shared__ __align__(16) unsigned short Ps[8][16][72];

  const unsigned short* Kbase = Kb + (size_t)b * 1025 * D_ + h * HD_;
  const unsigned short* Vbase = Vt + (size_t)bh * 128 * VTP;

  short8 qf[4];
  {
    const unsigned short* qrow = Qb + (size_t)(b * MK_ + q0 + w * 16 + l15) * D_ + h * HD_;
#pragma unroll
    for (int kk = 0; kk < 4; ++kk) qf[kk] = *(const short8*)(qrow + kk * 32 + g * 8);
  }

  f32x4 oacc[8] = {};
  float mrow[4], lrow[4];
#pragma unroll
  for (int r = 0; r < 4; ++r) { mrow[r] = -__builtin_inff(); lrow[r] = 0.f; }

  int qminw = q0 + w * 16;

  stage_k(Kbase, Ks[0], 0, w, lane);   // prologue: K tile 0
  int cur = 0;

  for (int t = 0; t < nt; ++t) {
    int kv0 = (t < nt - 1) ? t * 64 : MK_;
    stage_v(Vbase, Vts, kv0, w, lane);
    if (t + 1 < nt) {
      int kv1 = (t + 1 < nt - 1) ? (t + 1) * 64 : MK_;
      stage_k(Kbase, Ks[cur ^ 1], kv1, w, lane);
      asm volatile("s_waitcnt vmcnt(4)" ::: "memory");   // K(t) landed; V(t),K(t+1) in flight
    } else {
      asm volatile("s_waitcnt vmcnt(2)" ::: "memory");   // K(t) landed; V(t) in flight
    }
    __builtin_amdgcn_s_barrier();

    bool active = (t == nt - 1) || (t * 64 <= qminw + 15);
    f32x4 sacc[4] = {};
    if (active) {
      const unsigned short* ks = Ks[cur];
#pragma unroll
      for (int kk = 0; kk < 4; ++kk) {
#pragma unroll
        for (int nf = 0; nf < 4; ++nf) {
          int krow = nf * 16 + l15;
          int sw = (kk * 4 + g) ^ (krow & 7);
          short8 kf = *(const short8*)(ks + krow * 128 + sw * 8);
          sacc[nf] = __builtin_amdgcn_mfma_f32_16x16x32_bf16(qf[kk], kf, sacc[nf], 0, 0, 0);
        }
      }

      if (t == nt - 1) {
#pragma unroll
        for (int nf = 0; nf < 4; ++nf) {
          int col = nf * 16 + l15;
          if (col != 0) {
#pragma unroll
            for (int r = 0; r < 4; ++r) sacc[nf][r] = -1e9f;
          }
        }
      } else if (t * 64 + 63 > qminw) {
        int qb = qminw - t * 64 + g * 4;   // allow col <= qb + r
#pragma unroll
        for (int nf = 0; nf < 4; ++nf) {
          int col = nf * 16 + l15;
#pragma unroll
          for (int r = 0; r < 4; ++r)
            if (col > qb + r) sacc[nf][r] = -1e9f;
        }
      }

      // softmax part 1 (log2 domain, defer-max)
      float pm[4]; bool need = false;
#pragma unroll
      for (int r = 0; r < 4; ++r) {
        float mx = fmaxf(fmaxf(sacc[0][r], sacc[1][r]), fmaxf(sacc[2][r], sacc[3][r]));
        mx = fmaxf(mx, __shfl_xor(mx, 1));
        mx = fmaxf(mx, __shfl_xor(mx, 2));
        mx = fmaxf(mx, __shfl_xor(mx, 4));
        mx = fmaxf(mx, __shfl_xor(mx, 8));
        pm[r] = mx;
        need |= (mx > mrow[r] + 8.0f);
      }
      if (__any((int)need)) {
#pragma unroll
        for (int r = 0; r < 4; ++r) {
          float mnew = fmaxf(mrow[r], pm[r]);
          float sf = exp2f(mrow[r] - mnew);
          mrow[r] = mnew;
          lrow[r] *= sf;
#pragma unroll
          for (int i = 0; i < 8; ++i) oacc[i][r] *= sf;
        }
      }
      float rs[4] = {0.f, 0.f, 0.f, 0.f};
#pragma unroll
      for (int nf = 0; nf < 4; ++nf) {
#pragma unroll
        for (int r = 0; r < 4; ++r) {
          float p = exp2f(sacc[nf][r] - mrow[r]);
          sacc[nf][r] = p;
          rs[r] += p;
        }
      }
#pragma unroll
      for (int r = 0; r < 4; ++r) {
        float s = rs[r];
        s += __shfl_xor(s, 1);
        s += __shfl_xor(s, 2);
        s += __shfl_xor(s, 4);
        s += __shfl_xor(s, 8);
        lrow[r] += s;
      }
#pragma unroll
      for (int nf = 0; nf < 4; ++nf)
#pragma unroll
        for (int r = 0; r < 4; ++r)
          Ps[w][g * 4 + r][nf * 16 + l15] = f2bf(sacc[nf][r]);
    }

    if (t + 1 < nt) asm volatile("s_waitcnt vmcnt(2)" ::: "memory");  // V(t) landed
    else            asm volatile("s_waitcnt vmcnt(0)" ::: "memory");
    __builtin_amdgcn_s_barrier();

    if (active) {
#pragma unroll
      for (int kk = 0; kk < 2; ++kk) {
        short8 pf = *(const short8*)(&Ps[w][l15][kk * 32 + g * 8]);
#pragma unroll
        for (int nf = 0; nf < 8; ++nf) {
          int vrow = nf * 16 + l15;
          int sw = (kk * 4 + g) ^ (vrow & 7);
          short8 vf = *(const short8*)(Vts + vrow * 64 + sw * 8);
          oacc[nf] = __builtin_amdgcn_mfma_f32_16x16x32_bf16(pf, vf, oacc[nf], 0, 0, 0);
        }
      }
    }
    __builtin_amdgcn_s_barrier();   // protects Vts + Ks[cur^1 -> new cur] overwrite next iter
    cur ^= 1;
  }

#pragma unroll
  for (int nf = 0; nf < 8; ++nf) {
#pragma unroll
    for (int r = 0; r < 4; ++r) {
      size_t row = (size_t)b * MK_ + q0 + w * 16 + g * 4 + r;
      Ob[row * D_ + h * HD_ + nf * 16 + l15] = f2bf(oacc[nf][r] / lrow[r]);
    }
  }
}

// ------------------------------------------------------------------- launch
extern "C" void kernel_launch(void* const* d_in, const int* in_sizes, int n_in,
                              void* d_out, int out_size, void* d_ws, size_t ws_size,
                              hipStream_t stream) {
  const float* x    = (const float*)d_in[0];
  const void*  mask = d_in[1];
  const float* reg  = (const float*)d_in[2];
  const float* Wq   = (const float*)d_in[3];
  const float* bq   = (const float*)d_in[4];
  const float* Wk   = (const float*)d_in[5];
  const float* bk   = (const float*)d_in[6];
  const float* Wv   = (const float*)d_in[7];
  const float* bv   = (const float*)d_in[8];
  const float* Wrk  = (const float*)d_in[9];
  const float* brk  = (const float*)d_in[10];
  const float* Wrv  = (const float*)d_in[11];
  const float* brv  = (const float*)d_in[12];
  const float* Wo   = (const float*)d_in[13];
  const float* bo   = (const float*)d_in[14];

  char* ws = (char*)d_ws;
  int* flag            = (int*)ws;                       // 256 B
  int* rowmap          = (int*)(ws + 256);               // 32768 B
  unsigned char* sel   = (unsigned char*)(ws + 33024);   // 32768 B
  char* p = ws + 66048;
  unsigned short* sig = (unsigned short*)p;              p += (size_t)8192 * 2048 * 2;
  unsigned short* Qb  = (unsigned short*)p;              p += (size_t)8192 * 2048 * 2;
  unsigned short* Kb  = (unsigned short*)p;              p += (size_t)8200 * 2048 * 2;
  unsigned short* Vtb = (unsigned short*)p;              p += ((size_t)16384 * VTP + 64) * 2;
  unsigned short* Wbf = (unsigned short*)p;              p += (size_t)2048 * 2048 * 2;
  unsigned short* Ob  = sig;  // sig dead after V-GEMM

  detect_mask_kernel<<<1, 256, 0, stream>>>((const unsigned char*)mask, flag, sel);
  build_rowmap_kernel<<<8, 256, 0, stream>>>(mask, flag, rowmap, sel);
  copy_x_kernel<<<B_ * L_, 256, 0, stream>>>((const float4*)x, (float4*)d_out, sel);
  gather_sig_kernel<<<8192, 256, 0, stream>>>(x, rowmap, sig);
  reg_kv_kernel<<<1024, 256, 0, stream>>>(reg, Wrk, brk, Wrv, brv, Kb, Vtb);

  // fold 1/sqrt(HD) * log2(e) into Q so attn softmax uses exp2 directly
  const float qalpha = 0.08838834764831845f * 1.4426950408889634f;
  conv_bf16_kernel<<<2048, 256, 0, stream>>>(Wq, Wbf);
  gemm_bf_kernel<0><<<1024, 256, 0, stream>>>(sig, Wbf, bq, Qb, nullptr, qalpha);
  conv_bf16_kernel<<<2048, 256, 0, stream>>>(Wk, Wbf);
  gemm_bf_kernel<1><<<1024, 256, 0, stream>>>(sig, Wbf, bk, Kb, nullptr, 1.0f);
  conv_bf16_kernel<<<2048, 256, 0, stream>>>(Wv, Wbf);
  gemm_bf_kernel<3><<<1024, 256, 0, stream>>>(sig, Wbf, bv, Vtb, nullptr, 1.0f);
  attn_kernel<<<1024, 512, 0, stream>>>(Qb, Kb, Vtb, Ob);
  conv_bf16_kernel<<<2048, 256, 0, stream>>>(Wo, Wbf);
  gemm_bf_kernel<2><<<1024, 256, 0, stream>>>(Ob, Wbf, bo, d_out, rowmap, 1.0f);
}

// Round 4
// 549.780 us; speedup vs baseline: 2.0339x; 1.1963x over previous
//
#include <hip/hip_runtime.h>
#include <hip/hip_bf16.h>

#define B_  8
#define L_  4096
#define D_  2048
#define H_  16
#define HD_ 128
#define MK_ 1024
#define VTP 1040   // Vt row pitch (k dim, 1025 used + pad)

typedef __attribute__((ext_vector_type(8))) short short8;
typedef __attribute__((ext_vector_type(4))) float f32x4;

__device__ inline unsigned short f2bf(float f) {
  unsigned int u = __float_as_uint(f);
  unsigned int r = (u + 0x7fffu + ((u >> 16) & 1u)) >> 16;   // RNE
  return (unsigned short)r;
}

__device__ __forceinline__ void gload_lds16(const void* g, void* l) {
  __builtin_amdgcn_global_load_lds(
      (const __attribute__((address_space(1))) void*)g,
      (__attribute__((address_space(3))) void*)l, 16, 0, 0);
}

// ---------------------------------------------------------------- mask dtype
__global__ void detect_mask_kernel(const unsigned char* __restrict__ mask, int* flag,
                                   unsigned char* __restrict__ sel) {
  __shared__ int cnt;
  if (threadIdx.x == 0) cnt = 0;
  __syncthreads();
  for (int i = threadIdx.x; i < (B_ * L_) / 16; i += 256) ((int4*)sel)[i] = make_int4(0, 0, 0, 0);
  int local = 0;
  for (int i = threadIdx.x; i < B_ * L_; i += 256) local += (mask[i] != 0);
  atomicAdd(&cnt, local);
  __syncthreads();
  if (threadIdx.x == 0) {
    int t = 0;
    if (cnt == B_ * MK_)      t = 0; // u8 bool
    else if (cnt == 2 * MK_)  t = 1; // i32
    else if (cnt == 4 * MK_)  t = 2; // f32
    *flag = t;
  }
}

// ------------------------------------------------------- compaction / rowmap
__global__ void build_rowmap_kernel(const void* __restrict__ maskv,
                                    const int* __restrict__ flag,
                                    int* __restrict__ rowmap,
                                    unsigned char* __restrict__ sel) {
  int b = blockIdx.x;
  int tid = threadIdx.x;
  int t = *flag;
  __shared__ int cnts[256];
  unsigned char loc[16];
  int c = 0;
  for (int j = 0; j < 16; ++j) {
    int pos = tid * 16 + j;
    int mv;
    if (t == 1)      mv = ((const int*)maskv)[b * L_ + pos] != 0;
    else if (t == 2) mv = ((const float*)maskv)[b * L_ + pos] != 0.0f;
    else             mv = ((const unsigned char*)maskv)[b * L_ + pos] != 0;
    loc[j] = (unsigned char)mv; c += mv;
  }
  cnts[tid] = c;
  __syncthreads();
  for (int off = 1; off < 256; off <<= 1) {
    int v = (tid >= off) ? cnts[tid - off] : 0;
    __syncthreads();
    cnts[tid] += v;
    __syncthreads();
  }
  int rank = cnts[tid] - c;
  for (int j = 0; j < 16; ++j) {
    if (loc[j]) {
      if (rank < MK_) {
        int grow = b * L_ + tid * 16 + j;
        rowmap[b * MK_ + rank] = grow;
        sel[grow] = 1;
      }
      ++rank;
    }
  }
}

// -------------------------------------------------- copy x->out (skip selected)
__global__ __launch_bounds__(256) void copy_x_kernel(const float4* __restrict__ src,
                                                     float4* __restrict__ dst,
                                                     const unsigned char* __restrict__ sel) {
  int row = blockIdx.x;
  if (sel[row]) return;
  size_t base = (size_t)row * 512 + threadIdx.x;
  dst[base] = src[base];
  dst[base + 256] = src[base + 256];
}

// ------------------------------------------------------------- gather + bf16
__global__ __launch_bounds__(256) void gather_sig_kernel(const float* __restrict__ x,
                                                         const int* __restrict__ rowmap,
                                                         unsigned short* __restrict__ sig) {
  int row = blockIdx.x;
  const float* src = x + (size_t)rowmap[row] * D_;
  unsigned short* dst = sig + (size_t)row * D_;
  int tid = threadIdx.x;
  float4 a = ((const float4*)src)[tid * 2];
  float4 b4 = ((const float4*)src)[tid * 2 + 1];
  uint4 o;
  o.x = f2bf(a.x)  | ((unsigned)f2bf(a.y)  << 16);
  o.y = f2bf(a.z)  | ((unsigned)f2bf(a.w)  << 16);
  o.z = f2bf(b4.x) | ((unsigned)f2bf(b4.y) << 16);
  o.w = f2bf(b4.z) | ((unsigned)f2bf(b4.w) << 16);
  *(uint4*)(dst + tid * 8) = o;
}

// ---------------------------------------------------------- f32 -> bf16 weights
__global__ __launch_bounds__(256) void conv_bf16_kernel(const float* __restrict__ W,
                                                        unsigned short* __restrict__ Wb) {
  size_t i = ((size_t)blockIdx.x * 256 + threadIdx.x) * 8;
  float4 a = *(const float4*)(W + i);
  float4 b4 = *(const float4*)(W + i + 4);
  uint4 o;
  o.x = f2bf(a.x)  | ((unsigned)f2bf(a.y)  << 16);
  o.y = f2bf(a.z)  | ((unsigned)f2bf(a.w)  << 16);
  o.z = f2bf(b4.x) | ((unsigned)f2bf(b4.y) << 16);
  o.w = f2bf(b4.z) | ((unsigned)f2bf(b4.w) << 16);
  *(uint4*)(Wb + i) = o;
}

// -------------------------------------------- register K/V rows (batched over b)
__global__ __launch_bounds__(256) void reg_kv_kernel(
    const float* __restrict__ reg, const float* __restrict__ Wrk, const float* __restrict__ brk,
    const float* __restrict__ Wrv, const float* __restrict__ brv,
    unsigned short* __restrict__ Kb, unsigned short* __restrict__ Vt) {
  int gw = (blockIdx.x * 256 + threadIdx.x) >> 6;  // 4096 waves
  int lane = threadIdx.x & 63;
  int mat = gw >> 11;
  int n = gw & 2047;
  const float* W = mat ? Wrv : Wrk;
  const float* wrow = W + (size_t)n * D_;
  float s[8] = {};
  for (int j = 0; j < 8; ++j) {
    int e = j * 256 + lane * 4;
    float4 wv = *(const float4*)(wrow + e);
#pragma unroll
    for (int b = 0; b < 8; ++b) {
      float4 rv = *(const float4*)(reg + (size_t)b * D_ + e);
      s[b] += wv.x * rv.x + wv.y * rv.y + wv.z * rv.z + wv.w * rv.w;
    }
  }
#pragma unroll
  for (int off = 32; off; off >>= 1)
#pragma unroll
    for (int b = 0; b < 8; ++b) s[b] += __shfl_down(s[b], off);
  if (lane == 0) {
    float bias = (mat ? brv : brk)[n];
#pragma unroll
    for (int b = 0; b < 8; ++b) {
      unsigned short v = f2bf(s[b] + bias);
      if (mat) {
        Vt[(((size_t)b * 16 + (n >> 7)) * 128 + (n & 127)) * VTP + 1024] = v;
      } else {
        Kb[((size_t)b * 1025 + 1024) * D_ + n] = v;
      }
    }
  }
}

// ------------------------------------------------- 256x256 deep-pipelined GEMM
// C[m,n] = (sum_k A[m,k]*Bw[n,k] + bias[n]) * alpha ; A,Bw bf16 row-major (k-contig)
// M=8192, N=2048, K=2048. BK=32, 4 LDS buffers (128 KiB), 2-K-tile lookahead,
// counted vmcnt(4), 2 phases/K-tile, setprio around MFMA clusters.
// OUT_MODE 0: bf16 row=m | 1: bf16 row=m+(m>>10) | 2: f32 row=rowmap[m] | 3: Vt transposed
template<int OUT_MODE>
__global__ __launch_bounds__(512, 2) void gemm8_kernel(
    const unsigned short* __restrict__ A, const unsigned short* __restrict__ Bw,
    const float* __restrict__ bias, void* __restrict__ Cout,
    const int* __restrict__ rowmap, float alpha) {
  __shared__ __align__(16) unsigned short lds[4][2][8192];  // [buf][A/B][256 rows x 32 k]
  int tid = threadIdx.x, lane = tid & 63, w = tid >> 6;
  int g = lane >> 4, l15 = lane & 15;
  int wm = w >> 2, wn = w & 3;

  // XCD grouping: blocks sharing an A-panel (same mb, all 8 nb) land on one XCD.
  int bid = blockIdx.x;
  int xcd = bid & 7, j = bid >> 3;          // grid = 256 (32 mb x 8 nb)
  int mb = xcd * 4 + (j >> 3), nb = j & 7;
  int m0 = mb * 256, n0 = nb * 256;

  f32x4 acc[2][4][4] = {};

  // stage one 16KB chunk (c: 0=A, 1=B) of K-tile kt: 2 global_load_lds / thread
#define STAGE(kt, c) {                                                          \
    const unsigned short* src0 = (c) ? Bw : A;                                  \
    int base0 = (c) ? n0 : m0;                                                  \
    int sg = (lane & 3) ^ ((lane >> 3) & 3);                                    \
    _Pragma("unroll")                                                           \
    for (int i_ = 0; i_ < 2; ++i_) {                                            \
      int row = (w * 2 + i_) * 16 + (lane >> 2);                                \
      gload_lds16(src0 + (size_t)(base0 + row) * D_ + (kt) * 32 + sg * 8,       \
                  &lds[(kt) & 3][c][(w * 2 + i_) * 512]);                       \
    }                                                                           \
  }

  // prologue: tiles 0 and 1
  STAGE(0, 0); STAGE(0, 1);
  STAGE(1, 0); STAGE(1, 1);
  asm volatile("s_waitcnt vmcnt(4)" ::: "memory");   // tile 0 landed
  __builtin_amdgcn_s_barrier();

  int sw8 = (g ^ ((l15 >> 1) & 3)) * 8;              // swizzled 16B slot (ushort units)

  for (int kt = 0; kt < 64; ++kt) {
    const unsigned short* Abuf = &lds[kt & 3][0][0];
    const unsigned short* Bbuf = &lds[kt & 3][1][0];
    short8 af[4], bf[4];

    // ---- phase 0: B frags + A half 0 ----
#pragma unroll
    for (int nf = 0; nf < 4; ++nf)
      bf[nf] = *(const short8*)(Bbuf + (wn * 64 + nf * 16 + l15) * 32 + sw8);
#pragma unroll
    for (int mf = 0; mf < 4; ++mf)
      af[mf] = *(const short8*)(Abuf + (wm * 128 + mf * 16 + l15) * 32 + sw8);
    if (kt + 2 < 64) STAGE(kt + 2, 0);
    __builtin_amdgcn_s_barrier();
    asm volatile("s_waitcnt lgkmcnt(0)" ::: "memory");
    __builtin_amdgcn_sched_barrier(0);
    __builtin_amdgcn_s_setprio(1);
#pragma unroll
    for (int mf = 0; mf < 4; ++mf)
#pragma unroll
      for (int nf = 0; nf < 4; ++nf)
        acc[0][mf][nf] = __builtin_amdgcn_mfma_f32_16x16x32_bf16(af[mf], bf[nf], acc[0][mf][nf], 0, 0, 0);
    __builtin_amdgcn_s_setprio(0);
    __builtin_amdgcn_s_barrier();

    // ---- phase 1: A half 1 (B frags reused) ----
#pragma unroll
    for (int mf = 0; mf < 4; ++mf)
      af[mf] = *(const short8*)(Abuf + (wm * 128 + 64 + mf * 16 + l15) * 32 + sw8);
    if (kt + 2 < 64) STAGE(kt + 2, 1);
    __builtin_amdgcn_s_barrier();
    asm volatile("s_waitcnt lgkmcnt(0)" ::: "memory");
    __builtin_amdgcn_sched_barrier(0);
    __builtin_amdgcn_s_setprio(1);
#pragma unroll
    for (int mf = 0; mf < 4; ++mf)
#pragma unroll
      for (int nf = 0; nf < 4; ++nf)
        acc[1][mf][nf] = __builtin_amdgcn_mfma_f32_16x16x32_bf16(af[mf], bf[nf], acc[1][mf][nf], 0, 0, 0);
    __builtin_amdgcn_s_setprio(0);
    if (kt < 62)       asm volatile("s_waitcnt vmcnt(4)" ::: "memory");  // kt+1 landed
    else if (kt == 62) asm volatile("s_waitcnt vmcnt(0)" ::: "memory");
    __builtin_amdgcn_s_barrier();
  }
#undef STAGE

#pragma unroll
  for (int ph = 0; ph < 2; ++ph) {
#pragma unroll
    for (int mf = 0; mf < 4; ++mf) {
#pragma unroll
      for (int nf = 0; nf < 4; ++nf) {
        int nn = n0 + wn * 64 + nf * 16 + l15;
        float bvv = bias[nn];
        int m = m0 + wm * 128 + ph * 64 + mf * 16 + g * 4;
        if (OUT_MODE == 3) {
          int bb = m >> 10, tok = m & 1023;
          size_t base = (((size_t)bb * 16 + (nn >> 7)) * 128 + (nn & 127)) * VTP + tok;
          uint2 u;
          u.x = f2bf(acc[ph][mf][nf][0] + bvv) | ((unsigned)f2bf(acc[ph][mf][nf][1] + bvv) << 16);
          u.y = f2bf(acc[ph][mf][nf][2] + bvv) | ((unsigned)f2bf(acc[ph][mf][nf][3] + bvv) << 16);
          *(uint2*)((unsigned short*)Cout + base) = u;
        } else {
#pragma unroll
          for (int r = 0; r < 4; ++r) {
            float v = (acc[ph][mf][nf][r] + bvv) * alpha;
            if (OUT_MODE == 0) {
              ((unsigned short*)Cout)[(size_t)(m + r) * D_ + nn] = f2bf(v);
            } else if (OUT_MODE == 1) {
              int row = (m + r) + ((m + r) >> 10);
              ((unsigned short*)Cout)[(size_t)row * D_ + nn] = f2bf(v);
            } else {
              int row = rowmap[m + r];
              ((float*)Cout)[(size_t)row * D_ + nn] = v;
            }
          }
        }
      }
    }
  }
}

// ----------------------------------------------------------- flash attention
// Q pre-scaled by 1/sqrt(HD)*log2(e) -> scores already in log2 domain.
// Kb: [b][1025][2048] bf16 ; Vt: [(b*16+h)*128+d][VTP] bf16 (k-contig, transposed)
__device__ __forceinline__ void stage_k(const unsigned short* Kbase, unsigned short* dst,
                                        int kv0, int w, int lane) {
#pragma unroll
  for (int i = 0; i < 2; ++i) {
    int ib = w * 2 + i;
    int row = ib * 4 + (lane >> 4);
    int sl = (lane & 15) ^ (row & 7);
    int krow = kv0 + row; if (krow > MK_) krow = MK_;
    gload_lds16(Kbase + (size_t)krow * D_ + sl * 8, dst + ib * 512);
  }
}
__device__ __forceinline__ void stage_v(const unsigned short* Vbase, unsigned short* dst,
                                        int kv0, int w, int lane) {
#pragma unroll
  for (int i = 0; i < 2; ++i) {
    int ib = w * 2 + i;
    int row = ib * 8 + (lane >> 3);
    int sl = (lane & 7) ^ (row & 7);
    gload_lds16(Vbase + (size_t)row * VTP + kv0 + sl * 8, dst + ib * 512);
  }
}

__global__ __launch_bounds__(512) void attn_kernel(
    const unsigned short* __restrict__ Qb, const unsigned short* __restrict__ Kb,
    const unsigned short* __restrict__ Vt, unsigned short* __restrict__ Ob) {
  int bx = blockIdx.x;
  int qi = 7 - (bx >> 7);          // heavy blocks first
  int bh = bx & 127;
  int b = bh >> 4, h = bh & 15;
  int tid = threadIdx.x, lane = tid & 63, w = tid >> 6;
  int g = lane >> 4, l15 = lane & 15;
  int q0 = qi * 128;
  int nt = 2 * qi + 3;             // causal tiles + register tile

  __shared__ __align__(16) unsigned short Ks[2][64 * 128];
  __shared__ __align__(16) unsigned short Vts[128 * 64];
  __shared__ __align__(16) unsigned short Ps[8][16][72];

  const unsigned short* Kbase = Kb + (size_t)b * 1025 * D_ + h * HD_;
  const unsigned short* Vbase = Vt + (size_t)bh * 128 * VTP;

  short8 qf[4];
  {
    const unsigned short* qrow = Qb + (size_t)(b * MK_ + q0 + w * 16 + l15) * D_ + h * HD_;
#pragma unroll
    for (int kk = 0; kk < 4; ++kk) qf[kk] = *(const short8*)(qrow + kk * 32 + g * 8);
  }

  f32x4 oacc[8] = {};
  float mrow[4], lrow[4];
#pragma unroll
  for (int r = 0; r < 4; ++r) { mrow[r] = -__builtin_inff(); lrow[r] = 0.f; }

  int qminw = q0 + w * 16;

  stage_k(Kbase, Ks[0], 0, w, lane);   // prologue: K tile 0
  int cur = 0;

  for (int t = 0; t < nt; ++t) {
    int kv0 = (t < nt - 1) ? t * 64 : MK_;
    stage_v(Vbase, Vts, kv0, w, lane);
    if (t + 1 < nt) {
      int kv1 = (t + 1 < nt - 1) ? (t + 1) * 64 : MK_;
      stage_k(Kbase, Ks[cur ^ 1], kv1, w, lane);
      asm volatile("s_waitcnt vmcnt(4)" ::: "memory");   // K(t) landed
    } else {
      asm volatile("s_waitcnt vmcnt(2)" ::: "memory");
    }
    __builtin_amdgcn_s_barrier();

    bool active = (t == nt - 1) || (t * 64 <= qminw + 15);
    f32x4 sacc[4] = {};
    if (active) {
      const unsigned short* ks = Ks[cur];
#pragma unroll
      for (int kk = 0; kk < 4; ++kk) {
#pragma unroll
        for (int nf = 0; nf < 4; ++nf) {
          int krow = nf * 16 + l15;
          int sw = (kk * 4 + g) ^ (krow & 7);
          short8 kf = *(const short8*)(ks + krow * 128 + sw * 8);
          sacc[nf] = __builtin_amdgcn_mfma_f32_16x16x32_bf16(qf[kk], kf, sacc[nf], 0, 0, 0);
        }
      }

      if (t == nt - 1) {
#pragma unroll
        for (int nf = 0; nf < 4; ++nf) {
          int col = nf * 16 + l15;
          if (col != 0) {
#pragma unroll
            for (int r = 0; r < 4; ++r) sacc[nf][r] = -1e9f;
          }
        }
      } else if (t * 64 + 63 > qminw) {
        int qb = qminw - t * 64 + g * 4;
#pragma unroll
        for (int nf = 0; nf < 4; ++nf) {
          int col = nf * 16 + l15;
#pragma unroll
          for (int r = 0; r < 4; ++r)
            if (col > qb + r) sacc[nf][r] = -1e9f;
        }
      }

      // softmax (log2 domain, defer-max)
      float pm[4]; bool need = false;
#pragma unroll
      for (int r = 0; r < 4; ++r) {
        float mx = fmaxf(fmaxf(sacc[0][r], sacc[1][r]), fmaxf(sacc[2][r], sacc[3][r]));
        mx = fmaxf(mx, __shfl_xor(mx, 1));
        mx = fmaxf(mx, __shfl_xor(mx, 2));
        mx = fmaxf(mx, __shfl_xor(mx, 4));
        mx = fmaxf(mx, __shfl_xor(mx, 8));
        pm[r] = mx;
        need |= (mx > mrow[r] + 8.0f);
      }
      if (__any((int)need)) {
#pragma unroll
        for (int r = 0; r < 4; ++r) {
          float mnew = fmaxf(mrow[r], pm[r]);
          float sf = exp2f(mrow[r] - mnew);
          mrow[r] = mnew;
          lrow[r] *= sf;
#pragma unroll
          for (int i = 0; i < 8; ++i) oacc[i][r] *= sf;
        }
      }
      float rs[4] = {0.f, 0.f, 0.f, 0.f};
#pragma unroll
      for (int nf = 0; nf < 4; ++nf) {
#pragma unroll
        for (int r = 0; r < 4; ++r) {
          float p = exp2f(sacc[nf][r] - mrow[r]);
          sacc[nf][r] = p;
          rs[r] += p;
        }
      }
#pragma unroll
      for (int r = 0; r < 4; ++r) {
        float s = rs[r];
        s += __shfl_xor(s, 1);
        s += __shfl_xor(s, 2);
        s += __shfl_xor(s, 4);
        s += __shfl_xor(s, 8);
        lrow[r] += s;
      }
#pragma unroll
      for (int nf = 0; nf < 4; ++nf)
#pragma unroll
        for (int r = 0; r < 4; ++r)
          Ps[w][g * 4 + r][nf * 16 + l15] = f2bf(sacc[nf][r]);
    }

    if (t + 1 < nt) asm volatile("s_waitcnt vmcnt(2)" ::: "memory");  // V(t) landed
    else            asm volatile("s_waitcnt vmcnt(0)" ::: "memory");
    __builtin_amdgcn_s_barrier();

    if (active) {
#pragma unroll
      for (int kk = 0; kk < 2; ++kk) {
        short8 pf = *(const short8*)(&Ps[w][l15][kk * 32 + g * 8]);
#pragma unroll
        for (int nf = 0; nf < 8; ++nf) {
          int vrow = nf * 16 + l15;
          int sw = (kk * 4 + g) ^ (vrow & 7);
          short8 vf = *(const short8*)(Vts + vrow * 64 + sw * 8);
          oacc[nf] = __builtin_amdgcn_mfma_f32_16x16x32_bf16(pf, vf, oacc[nf], 0, 0, 0);
        }
      }
    }
    __builtin_amdgcn_s_barrier();
    cur ^= 1;
  }

#pragma unroll
  for (int nf = 0; nf < 8; ++nf) {
#pragma unroll
    for (int r = 0; r < 4; ++r) {
      size_t row = (size_t)b * MK_ + q0 + w * 16 + g * 4 + r;
      Ob[row * D_ + h * HD_ + nf * 16 + l15] = f2bf(oacc[nf][r] / lrow[r]);
    }
  }
}

// ------------------------------------------------------------------- launch
extern "C" void kernel_launch(void* const* d_in, const int* in_sizes, int n_in,
                              void* d_out, int out_size, void* d_ws, size_t ws_size,
                              hipStream_t stream) {
  const float* x    = (const float*)d_in[0];
  const void*  mask = d_in[1];
  const float* reg  = (const float*)d_in[2];
  const float* Wq   = (const float*)d_in[3];
  const float* bq   = (const float*)d_in[4];
  const float* Wk   = (const float*)d_in[5];
  const float* bk   = (const float*)d_in[6];
  const float* Wv   = (const float*)d_in[7];
  const float* bv   = (const float*)d_in[8];
  const float* Wrk  = (const float*)d_in[9];
  const float* brk  = (const float*)d_in[10];
  const float* Wrv  = (const float*)d_in[11];
  const float* brv  = (const float*)d_in[12];
  const float* Wo   = (const float*)d_in[13];
  const float* bo   = (const float*)d_in[14];

  char* ws = (char*)d_ws;
  int* flag            = (int*)ws;                       // 256 B
  int* rowmap          = (int*)(ws + 256);               // 32768 B
  unsigned char* sel   = (unsigned char*)(ws + 33024);   // 32768 B
  char* p = ws + 66048;
  unsigned short* sig = (unsigned short*)p;              p += (size_t)8192 * 2048 * 2;
  unsigned short* Qb  = (unsigned short*)p;              p += (size_t)8192 * 2048 * 2;
  unsigned short* Kb  = (unsigned short*)p;              p += (size_t)8200 * 2048 * 2;
  unsigned short* Vtb = (unsigned short*)p;              p += ((size_t)16384 * VTP + 64) * 2;
  unsigned short* Wbf = (unsigned short*)p;              p += (size_t)2048 * 2048 * 2;
  unsigned short* Ob  = sig;  // sig dead after V-GEMM

  detect_mask_kernel<<<1, 256, 0, stream>>>((const unsigned char*)mask, flag, sel);
  build_rowmap_kernel<<<8, 256, 0, stream>>>(mask, flag, rowmap, sel);
  copy_x_kernel<<<B_ * L_, 256, 0, stream>>>((const float4*)x, (float4*)d_out, sel);
  gather_sig_kernel<<<8192, 256, 0, stream>>>(x, rowmap, sig);
  reg_kv_kernel<<<1024, 256, 0, stream>>>(reg, Wrk, brk, Wrv, brv, Kb, Vtb);

  // fold 1/sqrt(HD) * log2(e) into Q so attn softmax uses exp2 directly
  const float qalpha = 0.08838834764831845f * 1.4426950408889634f;
  conv_bf16_kernel<<<2048, 256, 0, stream>>>(Wq, Wbf);
  gemm8_kernel<0><<<256, 512, 0, stream>>>(sig, Wbf, bq, Qb, nullptr, qalpha);
  conv_bf16_kernel<<<2048, 256, 0, stream>>>(Wk, Wbf);
  gemm8_kernel<1><<<256, 512, 0, stream>>>(sig, Wbf, bk, Kb, nullptr, 1.0f);
  conv_bf16_kernel<<<2048, 256, 0, stream>>>(Wv, Wbf);
  gemm8_kernel<3><<<256, 512, 0, stream>>>(sig, Wbf, bv, Vtb, nullptr, 1.0f);
  attn_kernel<<<1024, 512, 0, stream>>>(Qb, Kb, Vtb, Ob);
  conv_bf16_kernel<<<2048, 256, 0, stream>>>(Wo, Wbf);
  gemm8_kernel<2><<<256, 512, 0, stream>>>(Ob, Wbf, bo, d_out, rowmap, 1.0f);
}